// Round 2
// 528.768 us; speedup vs baseline: 1.8108x; 1.8108x over previous
//
#include <hip/hip_runtime.h>

// GroupedLinear: out[T,OUT] = x[T,IN] @ W[e]^T + bias[e], expert-ranged rows.
// E=8, IN=OUT=2048, T=16384. fp32 in/out, bf16 MFMA compute.
//
// Round 4: RESUBMIT of Round 3 (bench infra failed; no counters returned).
// Two-pass structure:
//   Pass 1: one-shot fp32->bf16 conversion of x and W into workspace
//           (memory-bound, ~402 MB moved, vectorized 8 elems/thread).
//   Pass 2: m97-structure bf16 GEMM — 128x128 tile, 4 waves @ 64x64,
//           BK=64, linear LDS (no pad), staging via
//           __builtin_amdgcn_global_load_lds width=16 (no VGPR roundtrip,
//           no in-loop conversion), 2-barrier K-loop.
// Falls back to the previous (verified) fused kernel if ws_size < 134 MB.

typedef __attribute__((ext_vector_type(8))) short short8;
typedef __attribute__((ext_vector_type(4))) float f32x4;

// round-to-nearest-even fp32 -> bf16 (inputs are finite; no NaN handling)
__device__ __forceinline__ unsigned short f2bf(float f) {
    unsigned u = __builtin_bit_cast(unsigned, f);
    u += 0x7FFFu + ((u >> 16) & 1u);
    return (unsigned short)(u >> 16);
}

// ---------------------------------------------------------------------------
// Pass 1: fp32 -> bf16 conversion, 8 elems/thread/iter, grid-stride.
// ---------------------------------------------------------------------------
__global__ __launch_bounds__(256)
void cvt_f32_bf16(const float* __restrict__ in, unsigned short* __restrict__ out, int n8)
{
    int i = blockIdx.x * blockDim.x + threadIdx.x;
    const int stride = gridDim.x * blockDim.x;
    const f32x4* __restrict__ in4 = (const f32x4*)in;
    short8* __restrict__ out8 = (short8*)out;
    for (; i < n8; i += stride) {
        f32x4 a = in4[2 * i];
        f32x4 b = in4[2 * i + 1];
        short8 o;
        o[0] = (short)f2bf(a.x); o[1] = (short)f2bf(a.y);
        o[2] = (short)f2bf(a.z); o[3] = (short)f2bf(a.w);
        o[4] = (short)f2bf(b.x); o[5] = (short)f2bf(b.y);
        o[6] = (short)f2bf(b.z); o[7] = (short)f2bf(b.w);
        out8[i] = o;
    }
}

// ---------------------------------------------------------------------------
// Pass 2: bf16 grouped GEMM, m97 structure (global_load_lds width=16).
// ---------------------------------------------------------------------------
__device__ __forceinline__ void gload_lds16(const unsigned short* gptr, unsigned short* lptr)
{
    __builtin_amdgcn_global_load_lds(
        (const __attribute__((address_space(1))) unsigned int*)gptr,
        (__attribute__((address_space(3))) unsigned int*)lptr,
        16, 0, 0);
}

__global__ __launch_bounds__(256, 2)
void grouped_gemm_bf16(const unsigned short* __restrict__ xb,
                       const unsigned short* __restrict__ wb,
                       const float* __restrict__ bias,
                       const int* __restrict__ tpe,
                       float* __restrict__ out)
{
    // linear layout, NO pad: global_load_lds writes base + lane*16 contiguously
    __shared__ __align__(16) unsigned short As[128 * 64];
    __shared__ __align__(16) unsigned short Bs[128 * 64];

    const int e = blockIdx.z;
    int off = 0, cnt = 0;
#pragma unroll
    for (int i = 0; i < 8; ++i) {
        int c = tpe[i];
        if (i < e) off += c;
        if (i == e) cnt = c;
    }
    const int m0 = blockIdx.y * 128;
    if (m0 >= cnt) return;               // no tokens for this tile (uniform branch)
    const int rows = min(128, cnt - m0); // valid rows in this tile
    const int row0 = off + m0;           // first global token row
    const int n0 = blockIdx.x * 128;     // output-column tile

    const int tid  = threadIdx.x;
    const int lane = tid & 63;
    const int wid  = tid >> 6;           // 0..3

    // Staging geometry: 16 LDS segments of 1 KiB each per tile (128x64 bf16).
    // Segment s = wid*4 + c; lane l covers tile row s*8 + l/8, cols (l&7)*8..+8.
    // LDS dest is wave-uniform (As + s*512); HW adds lane*16 bytes.
    const int lrow = lane >> 3;          // 0..7
    const int lcol = (lane & 7) * 8;     // 0,8,...,56

    const unsigned short* gA[4];
    const unsigned short* gB[4];
    unsigned short* lA[4];
    unsigned short* lB[4];
#pragma unroll
    for (int c = 0; c < 4; ++c) {
        const int s = wid * 4 + c;
        const int r = s * 8 + lrow;                 // 0..127 tile row
        const int ra = (r < rows) ? r : (rows - 1); // clamp A rows (ragged M)
        gA[c] = xb + (size_t)(row0 + ra) * 2048 + lcol;
        gB[c] = wb + (size_t)e * 4194304 + (size_t)(n0 + r) * 2048 + lcol;
        lA[c] = As + s * 512;
        lB[c] = Bs + s * 512;
    }

    // Wave / fragment coords (16x16x32 MFMA), identical to verified R2 kernel:
    //   A frag: m = lane&15, k = (lane>>4)*8 + j
    //   B frag: n = lane&15, k = (lane>>4)*8 + j
    //   D frag: col = lane&15, row = (lane>>4)*4 + reg
    const int fr = lane & 15;
    const int fq = lane >> 4;
    const int wm = (wid & 1) * 64;       // wave M origin in tile
    const int wn = (wid >> 1) * 64;      // wave N origin in tile

    f32x4 acc[4][4];
#pragma unroll
    for (int i = 0; i < 4; ++i)
#pragma unroll
        for (int j = 0; j < 4; ++j)
            acc[i][j] = (f32x4){0.f, 0.f, 0.f, 0.f};

    for (int kt = 0; kt < 32; ++kt) {
        __syncthreads();                 // previous tile fully consumed
#pragma unroll
        for (int c = 0; c < 4; ++c) {
            gload_lds16(gA[c], lA[c]);
            gload_lds16(gB[c], lB[c]);
            gA[c] += 64;
            gB[c] += 64;
        }
        __syncthreads();                 // drains vmcnt(0) -> tile ready

#pragma unroll
        for (int ks = 0; ks < 2; ++ks) {
            short8 af[4], bf[4];
#pragma unroll
            for (int i = 0; i < 4; ++i)
                af[i] = *(const short8*)(As + (wm + i * 16 + fr) * 64 + ks * 32 + fq * 8);
#pragma unroll
            for (int j = 0; j < 4; ++j)
                bf[j] = *(const short8*)(Bs + (wn + j * 16 + fr) * 64 + ks * 32 + fq * 8);
#pragma unroll
            for (int i = 0; i < 4; ++i)
#pragma unroll
                for (int j = 0; j < 4; ++j)
                    acc[i][j] = __builtin_amdgcn_mfma_f32_16x16x32_bf16(af[i], bf[j], acc[i][j], 0, 0, 0);
        }
    }

    // Epilogue: D row = wm + i*16 + fq*4 + r (M), col = n0 + wn + j*16 + fr (N)
#pragma unroll
    for (int j = 0; j < 4; ++j) {
        const int col = n0 + wn + j * 16 + fr;
        const float bv = bias[e * 2048 + col];
#pragma unroll
        for (int i = 0; i < 4; ++i) {
            const int rbase = wm + i * 16 + fq * 4;
#pragma unroll
            for (int r = 0; r < 4; ++r) {
                const int lr = rbase + r;
                if (lr < rows)
                    out[(size_t)(row0 + lr) * 2048 + col] = acc[i][j][r] + bv;
            }
        }
    }
}

// ---------------------------------------------------------------------------
// Fallback (previous verified fused kernel) for ws_size < 134 MB.
// ---------------------------------------------------------------------------
#define LDT 72  // LDS row stride in bf16 elems: 64 + 8 pad

__global__ __launch_bounds__(256, 2)
void grouped_gemm_f32(const float* __restrict__ x,
                      const float* __restrict__ w,
                      const float* __restrict__ bias,
                      const int* __restrict__ tpe,
                      float* __restrict__ out)
{
    __shared__ __align__(16) unsigned short As[128 * LDT];
    __shared__ __align__(16) unsigned short Bs[128 * LDT];

    const int e = blockIdx.z;
    int off = 0, cnt = 0;
#pragma unroll
    for (int i = 0; i < 8; ++i) {
        int c = tpe[i];
        if (i < e) off += c;
        if (i == e) cnt = c;
    }
    const int m0 = blockIdx.y * 128;
    if (m0 >= cnt) return;
    const int rows = min(128, cnt - m0);
    const int row0 = off + m0;
    const int n0 = blockIdx.x * 128;

    const int tid = threadIdx.x;
    const int sr = tid >> 4;
    const int sc = (tid & 15) * 4;

    const float* gA = x + (size_t)row0 * 2048 + sc;
    const float* gB = w + (size_t)e * 4194304 + (size_t)(n0 + sr) * 2048 + sc;

    int arow[8];
#pragma unroll
    for (int p = 0; p < 8; ++p) {
        int r = sr + p * 16;
        arow[p] = ((r < rows) ? r : (rows - 1)) * 2048;
    }

    const int lane = tid & 63;
    const int wid  = tid >> 6;
    const int wm   = (wid & 1) * 64;
    const int wn   = (wid >> 1) * 64;
    const int fr   = lane & 15;
    const int fq   = lane >> 4;

    f32x4 acc[4][4];
#pragma unroll
    for (int i = 0; i < 4; ++i)
#pragma unroll
        for (int j = 0; j < 4; ++j)
            acc[i][j] = (f32x4){0.f, 0.f, 0.f, 0.f};

    for (int kt = 0; kt < 32; ++kt) {
        const int kk = kt * 64;
        __syncthreads();
#pragma unroll
        for (int p = 0; p < 8; ++p) {
            f32x4 a = *(const f32x4*)(gA + arow[p] + kk);
            f32x4 b = *(const f32x4*)(gB + p * 32768 + kk);
            const int rbase = (sr + p * 16) * LDT + sc;
            As[rbase + 0] = f2bf(a.x);
            As[rbase + 1] = f2bf(a.y);
            As[rbase + 2] = f2bf(a.z);
            As[rbase + 3] = f2bf(a.w);
            Bs[rbase + 0] = f2bf(b.x);
            Bs[rbase + 1] = f2bf(b.y);
            Bs[rbase + 2] = f2bf(b.z);
            Bs[rbase + 3] = f2bf(b.w);
        }
        __syncthreads();

#pragma unroll
        for (int ks = 0; ks < 2; ++ks) {
            short8 af[4], bf[4];
#pragma unroll
            for (int i = 0; i < 4; ++i)
                af[i] = *(const short8*)(As + (wm + i * 16 + fr) * LDT + ks * 32 + fq * 8);
#pragma unroll
            for (int j = 0; j < 4; ++j)
                bf[j] = *(const short8*)(Bs + (wn + j * 16 + fr) * LDT + ks * 32 + fq * 8);
#pragma unroll
            for (int i = 0; i < 4; ++i)
#pragma unroll
                for (int j = 0; j < 4; ++j)
                    acc[i][j] = __builtin_amdgcn_mfma_f32_16x16x32_bf16(af[i], bf[j], acc[i][j], 0, 0, 0);
        }
    }

#pragma unroll
    for (int j = 0; j < 4; ++j) {
        const int col = n0 + wn + j * 16 + fr;
        const float bv = bias[e * 2048 + col];
#pragma unroll
        for (int i = 0; i < 4; ++i) {
            const int rbase = wm + i * 16 + fq * 4;
#pragma unroll
            for (int r = 0; r < 4; ++r) {
                const int lr = rbase + r;
                if (lr < rows)
                    out[(size_t)(row0 + lr) * 2048 + col] = acc[i][j][r] + bv;
            }
        }
    }
}

extern "C" void kernel_launch(void* const* d_in, const int* in_sizes, int n_in,
                              void* d_out, int out_size, void* d_ws, size_t ws_size,
                              hipStream_t stream) {
    const float* x    = (const float*)d_in[0];
    const float* w    = (const float*)d_in[1];
    const float* bias = (const float*)d_in[2];
    const int*   tpe  = (const int*)d_in[3];
    float* out = (float*)d_out;

    const size_t XE = (size_t)16384 * 2048;     // x elems
    const size_t WE = (size_t)8 * 2048 * 2048;  // w elems
    const size_t need = (XE + WE) * sizeof(unsigned short);  // 134,217,728 B

    if (ws_size >= need && d_ws != nullptr) {
        unsigned short* xb = (unsigned short*)d_ws;
        unsigned short* wbuf = xb + XE;
        // Pass 1: convert (x: 4,194,304 short8 groups; w: same)
        cvt_f32_bf16<<<2048, 256, 0, stream>>>(x, xb, (int)(XE / 8));
        cvt_f32_bf16<<<2048, 256, 0, stream>>>(w, wbuf, (int)(WE / 8));
        // Pass 2: grouped GEMM. grid: n-tiles (16), m-tiles (cap 2304/128=18), experts (8)
        dim3 grid(16, 18, 8);
        grouped_gemm_bf16<<<grid, 256, 0, stream>>>(xb, wbuf, bias, tpe, out);
    } else {
        dim3 grid(16, 18, 8);
        grouped_gemm_f32<<<grid, 256, 0, stream>>>(x, w, bias, tpe, out);
    }
}